// Round 11
// baseline (49.155 us; speedup 1.0000x reference)
//
#include <hip/hip_runtime.h>
#include <hip/hip_bf16.h>

#define NG 128
#define NT 16

// ws float layout:
//   gtab  [128][8]  : {b0,b1,b2,b3, phi, 0,0,0}                     (1024 f)
//   mdemd [128][16][2] : {md, exp(md)} interleaved                  (4096 f)
//   lgtab [128][20] : gammaln terms + phi*ln(phi) folded            (2560 f)
//   part  [64][nsp] : [quarter*16+t][sample]
#define GTAB_OFF 0
#define MDEMD_OFF 1024
#define LGTAB_OFF 5120
#define PART_OFF 8192
#define LN2 0.6931471805599453f
#define L2E 1.4426950408889634f
#define EXP2F(x) __builtin_amdgcn_exp2f(x)

__global__ void setup_kernel(const float* __restrict__ delta,
                             const float* __restrict__ beta,
                             const float* __restrict__ phi,
                             const float* __restrict__ mo,
                             float* __restrict__ ws,
                             float* __restrict__ out) {
    const int g = threadIdx.x;
    if (g == 0) out[0] = 0.0f;   // deterministic re-init every call
    if (g >= NG) return;

    const float lnfact[20] = {
        0.0f, 0.0f, 0.69314718f, 1.79175947f, 3.17805383f,
        4.78749174f, 6.57925121f, 8.52516132f, 10.60460286f, 12.80182744f,
        15.10441253f, 17.50230781f, 19.98721446f, 22.55216381f, 25.19122114f,
        27.89927134f, 30.67186007f, 33.50507341f, 36.39544517f, 39.33988415f};

    float ph = fminf(fmaxf(phi[g], 1.0f), 100.0f);
    float plp = ph * __logf(ph);

    ws[GTAB_OFF + g * 8 + 0] = beta[0 * NG + g];
    ws[GTAB_OFF + g * 8 + 1] = beta[1 * NG + g];
    ws[GTAB_OFF + g * 8 + 2] = beta[2 * NG + g];
    ws[GTAB_OFF + g * 8 + 3] = beta[3 * NG + g];
    ws[GTAB_OFF + g * 8 + 4] = ph;
    ws[GTAB_OFF + g * 8 + 5] = 0.0f;
    ws[GTAB_OFF + g * 8 + 6] = 0.0f;
    ws[GTAB_OFF + g * 8 + 7] = 0.0f;

#pragma unroll
    for (int t = 0; t < NT; ++t) {
        float md = mo[g * NT + t] * delta[g * NT + t];
        ws[MDEMD_OFF + g * 32 + 2 * t]     = md;
        ws[MDEMD_OFF + g * 32 + 2 * t + 1] = __expf(md);
    }

    float accn = 0.0f;
    ws[LGTAB_OFF + g * 20 + 0] = plp;
#pragma unroll
    for (int k = 1; k < 20; ++k) {
        accn += __logf(ph + (float)(k - 1));
        ws[LGTAB_OFF + g * 20 + k] = accn - lnfact[k] + plp;
    }
}

// Phase 1: block = 64 samples x 32 genes (quarter), 8 waves x 4 genes each.
// 3128 blocks, VGPR<=64 (launch_bounds 512,8) -> 8 waves/SIMD residency.
__global__ __launch_bounds__(512, 8) void nb_phase1(const float* __restrict__ expr,
                                                    const float* __restrict__ cov,
                                                    const float* __restrict__ sfv,
                                                    const float* __restrict__ ws,
                                                    float* __restrict__ part_out,
                                                    int ns, int nsp) {
    // staged quarter tables: gt 256 f, mdemd 1024 f, lg 640 f = 1920 f (7.7 KB)
    // reduction tree needs 4*64*17 = 4352 f (17.4 KB) -> union, 17.4 KB total
    __shared__ float s_mem[4352];
    float* __restrict__ s_gt = s_mem;            // [32][8]
    float* __restrict__ s_md = s_mem + 256;      // [32][16][2] interleaved
    float* __restrict__ s_lg = s_mem + 1280;     // [32][20]

    const int tid = threadIdx.x;
    const int tile = blockIdx.x >> 2;
    const int quarter = blockIdx.x & 3;

    if (tid < 64)
        ((float4*)s_gt)[tid] = ((const float4*)(ws + GTAB_OFF + quarter * 256))[tid];
    else if (tid < 320)
        ((float4*)s_md)[tid - 64] = ((const float4*)(ws + MDEMD_OFF + quarter * 1024))[tid - 64];
    else if (tid < 480)
        ((float4*)s_lg)[tid - 320] = ((const float4*)(ws + LGTAB_OFF + quarter * 640))[tid - 320];
    __syncthreads();

    const int lane = tid & 63;
    const int q = __builtin_amdgcn_readfirstlane(tid >> 6);  // wave id 0..7
    const int s = tile * 64 + lane;
    const bool valid = (s < ns);

    float acc[NT];
#pragma unroll
    for (int t = 0; t < NT; ++t) acc[t] = 0.0f;
    float hacc = 0.0f;

    float4 cv = make_float4(0.f, 0.f, 0.f, 0.f);
    float sf = 1.0f;
    if (valid) {
        cv = *reinterpret_cast<const float4*>(cov + (size_t)s * 4);
        sf = sfv[s];
    }
    const float lsf  = __logf(sf);
    const float lsf2 = lsf * L2E;

    // this wave's 4 genes; one float4 of k per lane
    float4 kv = make_float4(0.f, 0.f, 0.f, 0.f);
    if (valid)
        kv = *reinterpret_cast<const float4*>(expr + (size_t)s * NG + quarter * 32 + q * 4);
    float kb[4] = {kv.x, kv.y, kv.z, kv.w};

#pragma unroll
    for (int a = 0; a < 4; ++a) {
        const int gl = q * 4 + a;                          // local gene 0..31
        const float b0 = s_gt[gl * 8 + 0];
        const float b1 = s_gt[gl * 8 + 1];
        const float b2 = s_gt[gl * 8 + 2];
        const float b3 = s_gt[gl * 8 + 3];
        const float ph = s_gt[gl * 8 + 4];

        float e = fmaf(b3, cv.w, fmaf(b2, cv.z, fmaf(b1, cv.y, b0 * cv.x)));
        float c = EXP2F(fmaf(e, L2E, lsf2));               // sf * exp(e)
        float kf = kb[a];
        float lg = s_lg[gl * 20 + (int)kf];                // per-lane gather
        hacc += fmaf(kf, lsf + e, lg);
        float nkp2 = -(kf + ph) * LN2;
        const float* __restrict__ mp = s_md + gl * 32;
#pragma unroll
        for (int t = 0; t < NT; ++t) {
            float md  = mp[2 * t];                         // ds_read_b64 broadcast
            float emd = mp[2 * t + 1];
            float v = fmaf(c, emd, ph);                    // mu + phi
            acc[t] = fmaf(nkp2, __log2f(v), fmaf(kf, md, acc[t]));
        }
    }
#pragma unroll
    for (int t = 0; t < NT; ++t) acc[t] += hacc;

    // tree reduction 8 -> 4 -> 2 -> 1; red aliases table LDS (dead now)
    float (*red)[64][17] = (float (*)[64][17])s_mem;
    __syncthreads();

    if (q >= 4) {
#pragma unroll
        for (int t = 0; t < NT; ++t) red[q - 4][lane][t] = acc[t];
    }
    __syncthreads();
    if (q < 4) {
#pragma unroll
        for (int t = 0; t < NT; ++t) acc[t] += red[q][lane][t];
    }
    __syncthreads();
    if (q == 2 || q == 3) {
#pragma unroll
        for (int t = 0; t < NT; ++t) red[q - 2][lane][t] = acc[t];
    }
    __syncthreads();
    if (q < 2) {
#pragma unroll
        for (int t = 0; t < NT; ++t) acc[t] += red[q][lane][t];
    }
    __syncthreads();
    if (q == 1) {
#pragma unroll
        for (int t = 0; t < NT; ++t) red[0][lane][t] = acc[t];
    }
    __syncthreads();
    if (q == 0) {
#pragma unroll
        for (int t = 0; t < NT; ++t) {
            float v = acc[t] + red[0][lane][t];
            part_out[(size_t)(quarter * NT + t) * nsp + tile * 64 + lane] = v;
        }
    }
}

// Phase 2: per-sample combine of 4 quarter-partials + logsumexp + grand sum
__global__ __launch_bounds__(256) void nb_phase2(const float* __restrict__ part_in,
                                                 float* __restrict__ out,
                                                 int ns, int nsp) {
    const int s = blockIdx.x * 256 + threadIdx.x;
    float lp = 0.0f;
    if (s < ns) {
        float tot[NT];
#pragma unroll
        for (int t = 0; t < NT; ++t) tot[t] = 0.0f;
#pragma unroll
        for (int qt = 0; qt < 4; ++qt) {
#pragma unroll
            for (int t = 0; t < NT; ++t)
                tot[t] += part_in[(size_t)(qt * NT + t) * nsp + s];
        }
        float m = tot[0];
#pragma unroll
        for (int t = 1; t < NT; ++t) m = fmaxf(m, tot[t]);
        float sum = 0.0f;
#pragma unroll
        for (int t = 0; t < NT; ++t) sum += __expf(tot[t] - m);
        lp = m + __logf(sum);
    }
#pragma unroll
    for (int off = 32; off > 0; off >>= 1) lp += __shfl_down(lp, off);
    __shared__ float r[4];
    if ((threadIdx.x & 63) == 0) r[threadIdx.x >> 6] = lp;
    __syncthreads();
    if (threadIdx.x == 0) atomicAdd(out, r[0] + r[1] + r[2] + r[3]);
}

// Fallback: proven R6 single-phase kernel (35.7 us) if ws can't hold partials
__global__ __launch_bounds__(512) void nb_single(const float* __restrict__ expr,
                                                 const float* __restrict__ cov,
                                                 const float* __restrict__ sfv,
                                                 const float* __restrict__ ws,
                                                 float* __restrict__ out,
                                                 int ns) {
    __shared__ float s_tab[7680];
    const int tid = threadIdx.x;
#pragma unroll
    for (int i = 0; i < 4; ++i) {
        int idx = tid + i * 512;
        if (idx < 1920)
            *(float4*)&s_tab[idx * 4] = *(const float4*)(ws + idx * 4);
    }
    __syncthreads();

    const float* __restrict__ s_gt = s_tab + GTAB_OFF;
    const float* __restrict__ s_md = s_tab + MDEMD_OFF;
    const float* __restrict__ s_lg = s_tab + LGTAB_OFF;

    const int lane = tid & 63;
    const int q = __builtin_amdgcn_readfirstlane(tid >> 6);
    const int s = blockIdx.x * 64 + lane;
    const bool valid = (s < ns);

    float acc[NT];
#pragma unroll
    for (int t = 0; t < NT; ++t) acc[t] = 0.0f;
    float hacc = 0.0f;

    float4 cv = make_float4(0.f, 0.f, 0.f, 0.f);
    float sf = 1.0f;
    if (valid) {
        cv = *reinterpret_cast<const float4*>(cov + (size_t)s * 4);
        sf = sfv[s];
    }
    const float lsf  = __logf(sf);
    const float lsf2 = lsf * L2E;
    const int g0 = q * 16;

    for (int g4 = 0; g4 < 4; ++g4) {
        float4 kv = make_float4(0.f, 0.f, 0.f, 0.f);
        if (valid)
            kv = *reinterpret_cast<const float4*>(expr + (size_t)s * NG + g0 + g4 * 4);
        float kfv[4] = {kv.x, kv.y, kv.z, kv.w};
#pragma unroll
        for (int j = 0; j < 4; ++j) {
            const int g = g0 + g4 * 4 + j;
            const float b0 = s_gt[g * 8 + 0];
            const float b1 = s_gt[g * 8 + 1];
            const float b2 = s_gt[g * 8 + 2];
            const float b3 = s_gt[g * 8 + 3];
            const float ph = s_gt[g * 8 + 4];

            float e = fmaf(b3, cv.w, fmaf(b2, cv.z, fmaf(b1, cv.y, b0 * cv.x)));
            float c = EXP2F(fmaf(e, L2E, lsf2));
            float kf = kfv[j];
            float lg = s_lg[g * 20 + (int)kf];
            hacc += fmaf(kf, lsf + e, lg);
            float nkp2 = -(kf + ph) * LN2;
            const float* __restrict__ mp = s_md + g * 32;
#pragma unroll
            for (int t = 0; t < NT; ++t) {
                float v = fmaf(c, mp[2 * t + 1], ph);
                acc[t] = fmaf(nkp2, __log2f(v), fmaf(kf, mp[2 * t], acc[t]));
            }
        }
    }
#pragma unroll
    for (int t = 0; t < NT; ++t) acc[t] += hacc;

    float (*red)[64][17] = (float (*)[64][17])s_tab;
    __syncthreads();
    if (q >= 4) {
#pragma unroll
        for (int t = 0; t < NT; ++t) red[q - 4][lane][t] = acc[t];
    }
    __syncthreads();
    if (q < 4) {
#pragma unroll
        for (int t = 0; t < NT; ++t) acc[t] += red[q][lane][t];
    }
    __syncthreads();
    if (q == 2 || q == 3) {
#pragma unroll
        for (int t = 0; t < NT; ++t) red[q - 2][lane][t] = acc[t];
    }
    __syncthreads();
    if (q < 2) {
#pragma unroll
        for (int t = 0; t < NT; ++t) acc[t] += red[q][lane][t];
    }
    __syncthreads();
    if (q == 1) {
#pragma unroll
        for (int t = 0; t < NT; ++t) red[0][lane][t] = acc[t];
    }
    __syncthreads();
    if (q == 0) {
        float m = -1e30f;
#pragma unroll
        for (int t = 0; t < NT; ++t) {
            acc[t] += red[0][lane][t];
            m = fmaxf(m, acc[t]);
        }
        float sum = 0.0f;
#pragma unroll
        for (int t = 0; t < NT; ++t) sum += __expf(acc[t] - m);
        float lp = m + __logf(sum);
        if (!valid) lp = 0.0f;
#pragma unroll
        for (int off = 32; off > 0; off >>= 1) lp += __shfl_down(lp, off);
        if (lane == 0) atomicAdd(out, lp);
    }
}

extern "C" void kernel_launch(void* const* d_in, const int* in_sizes, int n_in,
                              void* d_out, int out_size, void* d_ws, size_t ws_size,
                              hipStream_t stream) {
    const float* delta = (const float*)d_in[0];
    const float* beta  = (const float*)d_in[1];
    const float* phi   = (const float*)d_in[2];
    const float* expr  = (const float*)d_in[3];
    const float* cov   = (const float*)d_in[4];
    const float* sf    = (const float*)d_in[5];
    const float* mo    = (const float*)d_in[6];
    float* out = (float*)d_out;
    float* ws  = (float*)d_ws;
    const int ns = in_sizes[5];

    setup_kernel<<<1, 128, 0, stream>>>(delta, beta, phi, mo, ws, out);

    const int tiles = (ns + 63) / 64;
    const int nsp = tiles * 64;
    const size_t need = ((size_t)PART_OFF + 64ull * (size_t)nsp) * 4ull;

    if (ws_size >= need) {
        float* part = ws + PART_OFF;
        nb_phase1<<<tiles * 4, 512, 0, stream>>>(expr, cov, sf, ws, part, ns, nsp);
        nb_phase2<<<(ns + 255) / 256, 256, 0, stream>>>(part, out, ns, nsp);
    } else {
        nb_single<<<tiles, 512, 0, stream>>>(expr, cov, sf, ws, out, ns);
    }
}

// Round 12
// 37.441 us; speedup vs baseline: 1.3129x; 1.3129x over previous
//
#include <hip/hip_runtime.h>
#include <hip/hip_bf16.h>

#define NG 128
#define NT 16

// ws float layout (transposed planar tables, 7680 floats):
//   bT   [4][128]  : beta transposed                        (512 f)
//   phT  [128]     : phi clamped                            (128 f)
//   pad             (384 f)
//   emdT [16][128] : exp(md) t-major                        (2048 f)
//   mdT  [16][128] : md t-major                             (2048 f)
//   lg   [128][20] : gammaln terms + phi*ln(phi)            (2560 f)
#define BT_OFF   0
#define PH_OFF   512
#define EMD_OFF  1024
#define MD_OFF   3072
#define LG_OFF   5120
#define TAB_FLOATS 7680
#define LN2 0.6931471805599453f
#define L2E 1.4426950408889634f
#define EXP2F(x) __builtin_amdgcn_exp2f(x)

__global__ void setup_kernel(const float* __restrict__ delta,
                             const float* __restrict__ beta,
                             const float* __restrict__ phi,
                             const float* __restrict__ mo,
                             float* __restrict__ ws,
                             float* __restrict__ out) {
    const int g = threadIdx.x;
    if (g == 0) out[0] = 0.0f;   // deterministic re-init every call
    if (g >= NG) return;

    const float lnfact[20] = {
        0.0f, 0.0f, 0.69314718f, 1.79175947f, 3.17805383f,
        4.78749174f, 6.57925121f, 8.52516132f, 10.60460286f, 12.80182744f,
        15.10441253f, 17.50230781f, 19.98721446f, 22.55216381f, 25.19122114f,
        27.89927134f, 30.67186007f, 33.50507341f, 36.39544517f, 39.33988415f};

    float ph = fminf(fmaxf(phi[g], 1.0f), 100.0f);
    float plp = ph * __logf(ph);

#pragma unroll
    for (int j = 0; j < 4; ++j)
        ws[BT_OFF + j * NG + g] = beta[j * NG + g];
    ws[PH_OFF + g] = ph;

#pragma unroll
    for (int t = 0; t < NT; ++t) {
        float md = mo[g * NT + t] * delta[g * NT + t];
        ws[EMD_OFF + t * NG + g] = __expf(md);
        ws[MD_OFF  + t * NG + g] = md;
    }

    float accn = 0.0f;
    ws[LG_OFF + g * 20 + 0] = plp;
#pragma unroll
    for (int k = 1; k < 20; ++k) {
        accn += __logf(ph + (float)(k - 1));
        ws[LG_OFF + g * 20 + k] = accn - lnfact[k] + plp;
    }
}

// Single-phase: block = 64 samples x 128 genes, 8 waves x 16 genes each.
// t-OUTER loop: per t, emd/md for 16 genes = 4+4 ds_read_b128 (broadcast).
// Per-gene sample state (c, nkp2, kf, ph) computed once, held in VGPRs.
__global__ __launch_bounds__(512) void nb_main(const float* __restrict__ expr,
                                               const float* __restrict__ cov,
                                               const float* __restrict__ sfv,
                                               const float* __restrict__ ws,
                                               float* __restrict__ out,
                                               int ns) {
    __shared__ float s_tab[TAB_FLOATS];          // 30.7 KB

    const int tid = threadIdx.x;
#pragma unroll
    for (int i = 0; i < 4; ++i) {
        int idx = tid + i * 512;
        if (idx < TAB_FLOATS / 4)
            *(float4*)&s_tab[idx * 4] = *(const float4*)(ws + idx * 4);
    }
    __syncthreads();

    const float* __restrict__ s_bT  = s_tab + BT_OFF;    // [4][128]
    const float* __restrict__ s_ph  = s_tab + PH_OFF;    // [128]
    const float* __restrict__ s_emd = s_tab + EMD_OFF;   // [16][128]
    const float* __restrict__ s_md  = s_tab + MD_OFF;    // [16][128]
    const float* __restrict__ s_lg  = s_tab + LG_OFF;    // [128][20]

    const int lane = tid & 63;
    const int q = __builtin_amdgcn_readfirstlane(tid >> 6);  // wave id 0..7
    const int s = blockIdx.x * 64 + lane;
    const bool valid = (s < ns);

    float4 cv = make_float4(0.f, 0.f, 0.f, 0.f);
    float sf = 1.0f;
    if (valid) {
        cv = *reinterpret_cast<const float4*>(cov + (size_t)s * 4);
        sf = sfv[s];
    }
    const float lsf  = __logf(sf);
    const float lsf2 = lsf * L2E;

    const int g0 = q * 16;   // wave-uniform gene strip

    // ---- per-gene prep: kf, e -> c, nkp2; hacc (one pass, vector LDS reads) ----
    float kf[16], cc[16], nkp[16], phv[16];
    float hacc = 0.0f;
    {
        // kf
#pragma unroll
        for (int g4 = 0; g4 < 4; ++g4) {
            float4 kv = make_float4(0.f, 0.f, 0.f, 0.f);
            if (valid)
                kv = *reinterpret_cast<const float4*>(expr + (size_t)s * NG + g0 + g4 * 4);
            kf[g4 * 4 + 0] = kv.x; kf[g4 * 4 + 1] = kv.y;
            kf[g4 * 4 + 2] = kv.z; kf[g4 * 4 + 3] = kv.w;
        }
        // e = cov . beta  (vector reads over g)
        float ev[16];
#pragma unroll
        for (int g4 = 0; g4 < 4; ++g4) {
            float4 b0 = *(const float4*)&s_bT[0 * NG + g0 + g4 * 4];
            float4 b1 = *(const float4*)&s_bT[1 * NG + g0 + g4 * 4];
            float4 b2 = *(const float4*)&s_bT[2 * NG + g0 + g4 * 4];
            float4 b3 = *(const float4*)&s_bT[3 * NG + g0 + g4 * 4];
            ev[g4 * 4 + 0] = fmaf(b3.x, cv.w, fmaf(b2.x, cv.z, fmaf(b1.x, cv.y, b0.x * cv.x)));
            ev[g4 * 4 + 1] = fmaf(b3.y, cv.w, fmaf(b2.y, cv.z, fmaf(b1.y, cv.y, b0.y * cv.x)));
            ev[g4 * 4 + 2] = fmaf(b3.z, cv.w, fmaf(b2.z, cv.z, fmaf(b1.z, cv.y, b0.z * cv.x)));
            ev[g4 * 4 + 3] = fmaf(b3.w, cv.w, fmaf(b2.w, cv.z, fmaf(b1.w, cv.y, b0.w * cv.x)));
        }
        // ph
#pragma unroll
        for (int g4 = 0; g4 < 4; ++g4) {
            float4 p = *(const float4*)&s_ph[g0 + g4 * 4];
            phv[g4 * 4 + 0] = p.x; phv[g4 * 4 + 1] = p.y;
            phv[g4 * 4 + 2] = p.z; phv[g4 * 4 + 3] = p.w;
        }
        // c, nkp2, hacc
#pragma unroll
        for (int gg = 0; gg < 16; ++gg) {
            cc[gg] = EXP2F(fmaf(ev[gg], L2E, lsf2));        // sf*exp(e)
            float lg = s_lg[(g0 + gg) * 20 + (int)kf[gg]];  // per-lane gather
            hacc += fmaf(kf[gg], lsf + ev[gg], lg);
            nkp[gg] = -(kf[gg] + phv[gg]) * LN2;
        }
    }

    // ---- t-outer main loop: per t, 8 broadcast b128 reads + 16x(3fma+log2) ----
    float acc[NT];
#pragma unroll 4
    for (int t = 0; t < NT; ++t) {
        float4 e0 = *(const float4*)&s_emd[t * NG + g0 + 0];
        float4 e1 = *(const float4*)&s_emd[t * NG + g0 + 4];
        float4 e2 = *(const float4*)&s_emd[t * NG + g0 + 8];
        float4 e3 = *(const float4*)&s_emd[t * NG + g0 + 12];
        float4 m0 = *(const float4*)&s_md[t * NG + g0 + 0];
        float4 m1 = *(const float4*)&s_md[t * NG + g0 + 4];
        float4 m2 = *(const float4*)&s_md[t * NG + g0 + 8];
        float4 m3 = *(const float4*)&s_md[t * NG + g0 + 12];
        const float ee[16] = {e0.x, e0.y, e0.z, e0.w, e1.x, e1.y, e1.z, e1.w,
                              e2.x, e2.y, e2.z, e2.w, e3.x, e3.y, e3.z, e3.w};
        const float mm[16] = {m0.x, m0.y, m0.z, m0.w, m1.x, m1.y, m1.z, m1.w,
                              m2.x, m2.y, m2.z, m2.w, m3.x, m3.y, m3.z, m3.w};
        float p0 = 0.0f, p1 = 0.0f;   // two chains for FMA ILP
#pragma unroll
        for (int gg = 0; gg < 16; gg += 2) {
            float v0 = fmaf(cc[gg], ee[gg], phv[gg]);
            p0 = fmaf(nkp[gg], __log2f(v0), fmaf(kf[gg], mm[gg], p0));
            float v1 = fmaf(cc[gg + 1], ee[gg + 1], phv[gg + 1]);
            p1 = fmaf(nkp[gg + 1], __log2f(v1), fmaf(kf[gg + 1], mm[gg + 1], p1));
        }
        acc[t] = p0 + p1 + hacc;
    }

    // ---- tree reduction 8 -> 4 -> 2 -> 1 through LDS aliased onto s_tab ----
    float (*red)[64][17] = (float (*)[64][17])s_tab;   // 4*64*17 = 4352 <= 7680
    __syncthreads();                                   // tables dead from here

    if (q >= 4) {
#pragma unroll
        for (int t = 0; t < NT; ++t) red[q - 4][lane][t] = acc[t];
    }
    __syncthreads();
    if (q < 4) {
#pragma unroll
        for (int t = 0; t < NT; ++t) acc[t] += red[q][lane][t];
    }
    __syncthreads();
    if (q == 2 || q == 3) {
#pragma unroll
        for (int t = 0; t < NT; ++t) red[q - 2][lane][t] = acc[t];
    }
    __syncthreads();
    if (q < 2) {
#pragma unroll
        for (int t = 0; t < NT; ++t) acc[t] += red[q][lane][t];
    }
    __syncthreads();
    if (q == 1) {
#pragma unroll
        for (int t = 0; t < NT; ++t) red[0][lane][t] = acc[t];
    }
    __syncthreads();
    if (q == 0) {
        float m = -1e30f;
#pragma unroll
        for (int t = 0; t < NT; ++t) {
            acc[t] += red[0][lane][t];
            m = fmaxf(m, acc[t]);
        }
        float sum = 0.0f;
#pragma unroll
        for (int t = 0; t < NT; ++t) sum += __expf(acc[t] - m);
        float lp = m + __logf(sum);
        if (!valid) lp = 0.0f;
#pragma unroll
        for (int off = 32; off > 0; off >>= 1) lp += __shfl_down(lp, off);
        if (lane == 0) atomicAdd(out, lp);
    }
}

extern "C" void kernel_launch(void* const* d_in, const int* in_sizes, int n_in,
                              void* d_out, int out_size, void* d_ws, size_t ws_size,
                              hipStream_t stream) {
    const float* delta = (const float*)d_in[0];
    const float* beta  = (const float*)d_in[1];
    const float* phi   = (const float*)d_in[2];
    const float* expr  = (const float*)d_in[3];
    const float* cov   = (const float*)d_in[4];
    const float* sf    = (const float*)d_in[5];
    const float* mo    = (const float*)d_in[6];
    float* out = (float*)d_out;
    float* ws  = (float*)d_ws;
    const int ns = in_sizes[5];

    setup_kernel<<<1, 128, 0, stream>>>(delta, beta, phi, mo, ws, out);

    const int tiles = (ns + 63) / 64;
    nb_main<<<tiles, 512, 0, stream>>>(expr, cov, sf, ws, out, ns);
}

// Round 13
// 36.000 us; speedup vs baseline: 1.3654x; 1.0400x over previous
//
#include <hip/hip_runtime.h>
#include <hip/hip_bf16.h>

#define NG 128
#define NT 16

// ws float layout (all tables contiguous, 7680 floats total):
//   gtab  [128][8]  : {betaT0..3, phi, 0, 0, 0}                      (1024 f)
//   mdemd [128][16][2] : {md, exp(md)} interleaved                   (4096 f)
//   lgtab [128][20] : gammaln(..)+phi*ln(phi) folded                 (2560 f)
#define GTAB_OFF 0
#define MDEMD_OFF 1024
#define LGTAB_OFF 5120
#define TAB_FLOATS 7680
#define LN2 0.6931471805599453f
#define L2E 1.4426950408889634f
#define EXP2F(x) __builtin_amdgcn_exp2f(x)

__global__ void setup_kernel(const float* __restrict__ delta,
                             const float* __restrict__ beta,
                             const float* __restrict__ phi,
                             const float* __restrict__ mo,
                             float* __restrict__ ws,
                             float* __restrict__ out) {
    const int g = threadIdx.x;
    if (g == 0) out[0] = 0.0f;   // deterministic re-init every call
    if (g >= NG) return;

    const float lnfact[20] = {
        0.0f, 0.0f, 0.69314718f, 1.79175947f, 3.17805383f,
        4.78749174f, 6.57925121f, 8.52516132f, 10.60460286f, 12.80182744f,
        15.10441253f, 17.50230781f, 19.98721446f, 22.55216381f, 25.19122114f,
        27.89927134f, 30.67186007f, 33.50507341f, 36.39544517f, 39.33988415f};

    float ph = fminf(fmaxf(phi[g], 1.0f), 100.0f);
    float plp = ph * __logf(ph);

    ws[GTAB_OFF + g * 8 + 0] = beta[0 * NG + g];
    ws[GTAB_OFF + g * 8 + 1] = beta[1 * NG + g];
    ws[GTAB_OFF + g * 8 + 2] = beta[2 * NG + g];
    ws[GTAB_OFF + g * 8 + 3] = beta[3 * NG + g];
    ws[GTAB_OFF + g * 8 + 4] = ph;
    ws[GTAB_OFF + g * 8 + 5] = 0.0f;
    ws[GTAB_OFF + g * 8 + 6] = 0.0f;
    ws[GTAB_OFF + g * 8 + 7] = 0.0f;

#pragma unroll
    for (int t = 0; t < NT; ++t) {
        float md = mo[g * NT + t] * delta[g * NT + t];
        ws[MDEMD_OFF + g * 32 + 2 * t]     = md;
        ws[MDEMD_OFF + g * 32 + 2 * t + 1] = __expf(md);
    }

    float accn = 0.0f;
    ws[LGTAB_OFF + g * 20 + 0] = plp;
#pragma unroll
    for (int k = 1; k < 20; ++k) {
        accn += __logf(ph + (float)(k - 1));
        ws[LGTAB_OFF + g * 20 + k] = accn - lnfact[k] + plp;
    }
}

// Single-phase: block = 64 samples x 128 genes, 8 waves x 16 genes each.
// IDENTICAL to the 35.7us champion except: gene loop forced to unroll 1
// (compact ~3KB body) with software-pipelined expr prefetch.
__global__ __launch_bounds__(512) void nb_main(const float* __restrict__ expr,
                                               const float* __restrict__ cov,
                                               const float* __restrict__ sfv,
                                               const float* __restrict__ ws,
                                               float* __restrict__ out,
                                               int ns) {
    __shared__ float s_tab[TAB_FLOATS];          // 30.7 KB total LDS

    const int tid = threadIdx.x;
#pragma unroll
    for (int i = 0; i < 4; ++i) {
        int idx = tid + i * 512;
        if (idx < TAB_FLOATS / 4)
            *(float4*)&s_tab[idx * 4] = *(const float4*)(ws + idx * 4);
    }
    __syncthreads();

    const float* __restrict__ s_gt = s_tab + GTAB_OFF;    // [128][8]
    const float* __restrict__ s_md = s_tab + MDEMD_OFF;   // [128][16][2]
    const float* __restrict__ s_lg = s_tab + LGTAB_OFF;   // [128][20]

    const int lane = tid & 63;
    const int q = __builtin_amdgcn_readfirstlane(tid >> 6);  // wave id 0..7
    const int s = blockIdx.x * 64 + lane;
    const bool valid = (s < ns);

    float acc[NT];
#pragma unroll
    for (int t = 0; t < NT; ++t) acc[t] = 0.0f;
    float hacc = 0.0f;

    float4 cv = make_float4(0.f, 0.f, 0.f, 0.f);
    float sf = 1.0f;
    if (valid) {
        cv = *reinterpret_cast<const float4*>(cov + (size_t)s * 4);
        sf = sfv[s];
    }
    const float lsf  = __logf(sf);
    const float lsf2 = lsf * L2E;

    const int g0 = q * 16;   // wave-uniform gene strip (16 genes)
    const float* __restrict__ exbase = expr + (size_t)s * NG + g0;

    // software-pipelined compact loop: 4 iterations x 4 genes (unroll 1)
    float4 kv_cur = make_float4(0.f, 0.f, 0.f, 0.f);
    if (valid) kv_cur = *reinterpret_cast<const float4*>(exbase);

#pragma unroll 1
    for (int g4 = 0; g4 < 4; ++g4) {
        // prefetch next iteration's k values (hidden under this body)
        float4 kv_next = make_float4(0.f, 0.f, 0.f, 0.f);
        if (valid && g4 < 3)
            kv_next = *reinterpret_cast<const float4*>(exbase + (g4 + 1) * 4);
        const float kfv[4] = {kv_cur.x, kv_cur.y, kv_cur.z, kv_cur.w};
#pragma unroll
        for (int j = 0; j < 4; ++j) {
            const int g = g0 + g4 * 4 + j;
            const float b0 = s_gt[g * 8 + 0];
            const float b1 = s_gt[g * 8 + 1];
            const float b2 = s_gt[g * 8 + 2];
            const float b3 = s_gt[g * 8 + 3];
            const float ph = s_gt[g * 8 + 4];

            float e = fmaf(b3, cv.w, fmaf(b2, cv.z, fmaf(b1, cv.y, b0 * cv.x)));
            float c = EXP2F(fmaf(e, L2E, lsf2));           // sf * exp(e)
            float kf = kfv[j];
            float lg = s_lg[g * 20 + (int)kf];             // per-lane gather
            hacc += fmaf(kf, lsf + e, lg);
            float nkp2 = -(kf + ph) * LN2;
            const float* __restrict__ mp = s_md + g * 32;
#pragma unroll
            for (int t = 0; t < NT; ++t) {
                float md  = mp[2 * t];                     // ds_read_b64 broadcast
                float emd = mp[2 * t + 1];
                float v = fmaf(c, emd, ph);                // mu + phi
                acc[t] = fmaf(nkp2, __log2f(v), fmaf(kf, md, acc[t]));
            }
        }
        kv_cur = kv_next;
    }
#pragma unroll
    for (int t = 0; t < NT; ++t) acc[t] += hacc;

    // ---- tree reduction 8 -> 4 -> 2 -> 1 through LDS aliased onto s_tab ----
    float (*red)[64][17] = (float (*)[64][17])s_tab;   // 4*64*17 = 4352 <= 7680
    __syncthreads();                                   // tables dead from here

    if (q >= 4) {
#pragma unroll
        for (int t = 0; t < NT; ++t) red[q - 4][lane][t] = acc[t];
    }
    __syncthreads();
    if (q < 4) {
#pragma unroll
        for (int t = 0; t < NT; ++t) acc[t] += red[q][lane][t];
    }
    __syncthreads();
    if (q == 2 || q == 3) {
#pragma unroll
        for (int t = 0; t < NT; ++t) red[q - 2][lane][t] = acc[t];
    }
    __syncthreads();
    if (q < 2) {
#pragma unroll
        for (int t = 0; t < NT; ++t) acc[t] += red[q][lane][t];
    }
    __syncthreads();
    if (q == 1) {
#pragma unroll
        for (int t = 0; t < NT; ++t) red[0][lane][t] = acc[t];
    }
    __syncthreads();
    if (q == 0) {
        float m = -1e30f;
#pragma unroll
        for (int t = 0; t < NT; ++t) {
            acc[t] += red[0][lane][t];
            m = fmaxf(m, acc[t]);
        }
        float sum = 0.0f;
#pragma unroll
        for (int t = 0; t < NT; ++t) sum += __expf(acc[t] - m);
        float lp = m + __logf(sum);
        if (!valid) lp = 0.0f;
#pragma unroll
        for (int off = 32; off > 0; off >>= 1) lp += __shfl_down(lp, off);
        if (lane == 0) atomicAdd(out, lp);
    }
}

extern "C" void kernel_launch(void* const* d_in, const int* in_sizes, int n_in,
                              void* d_out, int out_size, void* d_ws, size_t ws_size,
                              hipStream_t stream) {
    const float* delta = (const float*)d_in[0];
    const float* beta  = (const float*)d_in[1];
    const float* phi   = (const float*)d_in[2];
    const float* expr  = (const float*)d_in[3];
    const float* cov   = (const float*)d_in[4];
    const float* sf    = (const float*)d_in[5];
    const float* mo    = (const float*)d_in[6];
    float* out = (float*)d_out;
    float* ws  = (float*)d_ws;
    const int ns = in_sizes[5];

    setup_kernel<<<1, 128, 0, stream>>>(delta, beta, phi, mo, ws, out);

    const int tiles = (ns + 63) / 64;
    nb_main<<<tiles, 512, 0, stream>>>(expr, cov, sf, ws, out, ns);
}